// Round 1
// baseline (230.806 us; speedup 1.0000x reference)
//
#include <hip/hip_runtime.h>
#include <hip/hip_bf16.h>

#define B_  64
#define P_  8732
#define C_  81
#define M_  20
#define BLK 256
#define CEB 128   // priors per block in CE kernel

// ---------------- Kernel A: match + encode + loc loss + target class ----------------
__global__ __launch_bounds__(BLK) void match_kernel(
    const float* __restrict__ pred_loc, const float* __restrict__ priors,
    const float* __restrict__ tboxes, const int* __restrict__ tlabels,
    int* __restrict__ tclass, float* __restrict__ loc_sum, int* __restrict__ pos_cnt)
{
    const int b = blockIdx.x;
    const int tid = threadIdx.x;
    __shared__ float s_gt[M_][4];
    __shared__ float s_ga[M_];
    __shared__ int   s_lab[M_];
    __shared__ int   s_truth[P_];
    __shared__ float s_red[M_][4];
    __shared__ int   s_redp[M_][4];
    __shared__ float s_w[4];
    __shared__ int   s_wi[4];

    if (tid < M_*4) ((float*)s_gt)[tid] = tboxes[(size_t)b*M_*4 + tid];
    if (tid < M_)   s_lab[tid] = tlabels[(size_t)b*M_ + tid];
    __syncthreads();
    if (tid < M_) {
        float x0=s_gt[tid][0], y0=s_gt[tid][1], x1=s_gt[tid][2], y1=s_gt[tid][3];
        s_ga[tid] = (x1-x0)*(y1-y0);
    }
    __syncthreads();

    float lb[M_]; int lp[M_];
    #pragma unroll
    for (int m=0; m<M_; ++m) { lb[m] = -1.0f; lp[m] = 0x7FFFFFFF; }

    const float4* pr4 = (const float4*)priors;
    for (int p = tid; p < P_; p += BLK) {
        float4 pc = pr4[p];
        float px0 = pc.x - pc.z*0.5f, py0 = pc.y - pc.w*0.5f;
        float px1 = pc.x + pc.z*0.5f, py1 = pc.y + pc.w*0.5f;
        float pa = pc.z * pc.w;
        float best = -1.0f; int bg = 0;
        #pragma unroll
        for (int m=0; m<M_; ++m) {
            float ix0 = fmaxf(s_gt[m][0], px0);
            float iy0 = fmaxf(s_gt[m][1], py0);
            float ix1 = fminf(s_gt[m][2], px1);
            float iy1 = fminf(s_gt[m][3], py1);
            float iw = fmaxf(ix1-ix0, 0.f), ih = fmaxf(iy1-iy0, 0.f);
            float inter = iw*ih;
            float iou = inter / (s_ga[m] + pa - inter + 1e-10f);
            if (iou > best) { best = iou; bg = m; }           // first-max tie rule
            if (iou > lb[m] || (iou == lb[m] && p < lp[m])) { lb[m]=iou; lp[m]=p; }
        }
        s_truth[p] = (best >= 0.5f) ? bg : -1;
    }

    const int lane = tid & 63, wid = tid >> 6;
    #pragma unroll
    for (int m=0; m<M_; ++m) {
        float v = lb[m]; int ip = lp[m];
        for (int off=32; off; off>>=1) {
            float ov = __shfl_down(v, off); int op = __shfl_down(ip, off);
            if (ov > v || (ov == v && op < ip)) { v = ov; ip = op; }
        }
        if (lane == 0) { s_red[m][wid] = v; s_redp[m][wid] = ip; }
    }
    __syncthreads();
    if (tid == 0) {
        for (int m=0; m<M_; ++m) {
            float v = s_red[m][0]; int ip = s_redp[m][0];
            for (int w=1; w<4; ++w) {
                float ov = s_red[m][w]; int op = s_redp[m][w];
                if (ov > v || (ov == v && op < ip)) { v = ov; ip = op; }
            }
            s_truth[ip] = m;   // ascending m: last write wins (numpy scatter)
        }
    }
    __syncthreads();

    const float4* pl4 = (const float4*)pred_loc;
    float acc = 0.f; int pcnt = 0;
    for (int p = tid; p < P_; p += BLK) {
        int t = s_truth[p];
        int cls = 0;
        if (t >= 0) {
            cls = s_lab[t];
            float4 pc = pr4[p];
            float gx0=s_gt[t][0], gy0=s_gt[t][1], gx1=s_gt[t][2], gy1=s_gt[t][3];
            float gcx=(gx0+gx1)*0.5f, gcy=(gy0+gy1)*0.5f, gw=gx1-gx0, gh=gy1-gy0;
            float e0 = (gcx - pc.x) / (pc.z * 0.1f);
            float e1 = (gcy - pc.y) / (pc.w * 0.1f);
            float e2 = __logf(gw / pc.z + 1e-5f) * 5.0f;   // /0.2
            float e3 = __logf(gh / pc.w + 1e-5f) * 5.0f;
            float4 pl = pl4[(size_t)b*P_ + p];
            float d0 = pl.x-e0, d1 = pl.y-e1, d2 = pl.z-e2, d3 = pl.w-e3;
            float a0 = fabsf(d0), a1 = fabsf(d1), a2 = fabsf(d2), a3 = fabsf(d3);
            acc += (a0<1.f ? 0.5f*d0*d0 : a0-0.5f)
                 + (a1<1.f ? 0.5f*d1*d1 : a1-0.5f)
                 + (a2<1.f ? 0.5f*d2*d2 : a2-0.5f)
                 + (a3<1.f ? 0.5f*d3*d3 : a3-0.5f);
            pcnt++;
        }
        tclass[(size_t)b*P_ + p] = cls;
    }
    for (int off=32; off; off>>=1) { acc += __shfl_down(acc, off); pcnt += __shfl_down(pcnt, off); }
    if (lane == 0) { s_w[wid] = acc; s_wi[wid] = pcnt; }
    __syncthreads();
    if (tid == 0) {
        float a = 0.f; int c = 0;
        for (int w=0; w<4; ++w) { a += s_w[w]; c += s_wi[w]; }
        atomicAdd(loc_sum, a);
        pos_cnt[b] = c;
    }
}

// ---------------- Kernel B: cross-entropy per prior (memory-dominant) ----------------
__global__ __launch_bounds__(BLK) void ce_kernel(
    const float* __restrict__ pred_conf, const int* __restrict__ tclass,
    float* __restrict__ ce_out)
{
    __shared__ float sc[CEB * C_];
    const size_t base = (size_t)blockIdx.x * CEB;
    const float4* src = (const float4*)(pred_conf + base * C_);
    float4* dst = (float4*)sc;
    const int NV = CEB * C_ / 4;   // 2592
    for (int i = threadIdx.x; i < NV; i += BLK) dst[i] = src[i];
    __syncthreads();

    const int lp   = threadIdx.x >> 1;
    const int half = threadIdx.x & 1;
    const float* row = &sc[lp * C_];
    const int c0 = half * 41;
    const int cn = 41 - half;      // 41 or 40
    float mx = -1e30f;
    for (int c = 0; c < cn; ++c) mx = fmaxf(mx, row[c0 + c]);
    mx = fmaxf(mx, __shfl_xor(mx, 1));
    float s = 0.f;
    for (int c = 0; c < cn; ++c) s += __expf(row[c0 + c] - mx);
    s += __shfl_xor(s, 1);
    const size_t bp = base + lp;
    const int t = tclass[bp];
    if (half == 0) ce_out[bp] = mx + __logf(s) - row[t];
}

// ---------------- Kernel C: per-row radix-select top-k hard negatives ----------------
__global__ __launch_bounds__(BLK) void select_kernel(
    const float* __restrict__ ce, const int* __restrict__ tclass,
    const int* __restrict__ pos_cnt, float* __restrict__ conf_sum,
    float* __restrict__ mask_cnt)
{
    const int b = blockIdx.x; const int tid = threadIdx.x;
    const float* cerow = ce + (size_t)b * P_;
    const int*   tcrow = tclass + (size_t)b * P_;
    const int pos = pos_cnt[b];
    const unsigned k = (unsigned)min(3 * pos, P_ - 1);

    __shared__ unsigned hist[256];
    __shared__ unsigned s_prefix, s_remk, s_cntgt;
    if (tid == 0) { s_prefix = 0u; s_remk = k; s_cntgt = 0u; }
    __syncthreads();

    for (int pass = 3; pass >= 0; --pass) {
        hist[tid] = 0u;
        __syncthreads();
        const unsigned prefix = s_prefix;
        const int shift = pass * 8;
        const unsigned pmask = (pass == 3) ? 0u : (0xFFFFFFFFu << (shift + 8));
        for (int i = tid; i < P_; i += BLK) {
            const int tc = tcrow[i];
            const float v = (tc > 0) ? 0.f : cerow[i];
            const unsigned u = __float_as_uint(v);
            if ((u & pmask) == prefix) atomicAdd(&hist[(u >> shift) & 0xFFu], 1u);
        }
        __syncthreads();
        if (tid == 0) {
            unsigned acc = 0, remk = s_remk; int chosen = 0;
            for (int bin = 255; bin >= 0; --bin) {
                const unsigned c = hist[bin];
                if (acc + c >= remk) { chosen = bin; break; }
                acc += c;
            }
            s_cntgt += acc;
            s_remk = remk - acc;
            s_prefix = prefix | ((unsigned)chosen << shift);
        }
        __syncthreads();
    }

    const unsigned Tbits = s_prefix;
    const float T = __uint_as_float(Tbits);
    const unsigned cnt_gt = s_cntgt;
    const unsigned sel_eq = s_remk;   // = k - cnt_gt

    float sgt = 0.f, sp = 0.f;
    for (int i = tid; i < P_; i += BLK) {
        const int tc = tcrow[i]; const float cv = cerow[i];
        if (tc > 0) sp += cv;
        else if (cv > T) sgt += cv;
    }
    for (int off=32; off; off>>=1) { sgt += __shfl_down(sgt, off); sp += __shfl_down(sp, off); }
    __shared__ float rs[4], rq[4];
    const int lane = tid & 63, wid = tid >> 6;
    if (lane == 0) { rs[wid] = sgt; rq[wid] = sp; }
    __syncthreads();
    if (tid == 0) {
        float a = 0.f, c = 0.f;
        for (int w = 0; w < 4; ++w) { a += rs[w]; c += rq[w]; }
        float neg_sum, mc;
        if (Tbits != 0u) { neg_sum = a + (float)sel_eq * T; mc = (float)(pos + (int)k); }
        else             { neg_sum = a;                     mc = (float)(pos + (int)cnt_gt); }
        atomicAdd(conf_sum, c + neg_sum);
        atomicAdd(mask_cnt, mc);
    }
}

// ---------------- Kernel D: finalize ----------------
__global__ void finalize_kernel(const float* __restrict__ accums, float* __restrict__ out)
{
    out[0] = accums[0] / (float)B_;                 // loc_loss
    out[1] = accums[1] / accums[2] / (float)B_;     // conf_loss
}

extern "C" void kernel_launch(void* const* d_in, const int* in_sizes, int n_in,
                              void* d_out, int out_size, void* d_ws, size_t ws_size,
                              hipStream_t stream) {
    (void)in_sizes; (void)n_in; (void)out_size; (void)ws_size;
    const float* pred_loc  = (const float*)d_in[0];
    const float* pred_conf = (const float*)d_in[1];
    const float* priors    = (const float*)d_in[2];
    const float* tboxes    = (const float*)d_in[3];
    const int*   tlabels   = (const int*)d_in[4];
    float* out = (float*)d_out;

    const size_t BP = (size_t)B_ * P_;
    char* ws = (char*)d_ws;
    int*   tclass  = (int*)ws;                        // BP ints
    float* ce      = (float*)(ws + BP * 4);           // BP floats
    int*   pos_cnt = (int*)(ws + BP * 8);             // B_ ints
    float* accums  = (float*)(ws + BP * 8 + 256);     // [loc_sum, conf_sum, mask_cnt]

    hipMemsetAsync(accums, 0, 3 * sizeof(float), stream);

    match_kernel<<<B_, BLK, 0, stream>>>(pred_loc, priors, tboxes, tlabels,
                                         tclass, &accums[0], pos_cnt);
    const int nblk_ce = (int)(BP / CEB);  // 4366, exact
    ce_kernel<<<nblk_ce, BLK, 0, stream>>>(pred_conf, tclass, ce);
    select_kernel<<<B_, BLK, 0, stream>>>(ce, tclass, pos_cnt, &accums[1], &accums[2]);
    finalize_kernel<<<1, 1, 0, stream>>>(accums, out);
}